// Round 15
// baseline (232.693 us; speedup 1.0000x reference)
//
#include <hip/hip_runtime.h>
#include <hip/hip_fp16.h>
#include <math.h>

// B=65536 rows, DIM=256, OUT=10.
// z = x@w_in + b_in; 4x { z = (z + tanh(z) + b_i) @ inv(W_i) }; out = softmax(z@w_out + b_out).
// Newton on a linear system converges in one step => z = c @ W^{-1}.
// Round 15: ONE kernel. Blocks 0..383 compute inv(W) = 6I-15W+20W^2-15W^3+6W^4-W^5
// (degree-5 Horner, 4-row slabs) + pack w_in/w_out, then release a device-scope
// semaphore; all 1024 blocks overlap x-staging with phase 1, acquire-spin, then
// run the round-14 fused MFMA pipeline. Deadlock-safe: grid 1024 = 256 CU x 4
// blocks/CU, guaranteed co-resident (launch_bounds(256,4), 32 KB LDS, 64 VGPR).

typedef __attribute__((ext_vector_type(8))) short short8;
typedef __attribute__((ext_vector_type(4))) float f32x4;

// ---- helpers ----
__device__ __forceinline__ float tanh_fast(float x) {
#if __has_builtin(__builtin_amdgcn_exp2f)
  float e = __builtin_amdgcn_exp2f(x * 2.8853900817779268f);
#else
  float e = __expf(2.0f * x);
#endif
  return 1.0f - 2.0f * __builtin_amdgcn_rcpf(e + 1.0f);
}
__device__ __forceinline__ unsigned rn_pair16(float v0, float v1) {
  __half2 h = __floats2half2_rn(v0, v1);
  return *reinterpret_cast<unsigned*>(&h);
}
__device__ __forceinline__ unsigned rtz_pair16(float v0, float v1) {
#if __has_builtin(__builtin_amdgcn_cvt_pkrtz)
  typedef __fp16 h2v __attribute__((ext_vector_type(2)));
  h2v h = __builtin_amdgcn_cvt_pkrtz(v0, v1);
  return *reinterpret_cast<unsigned*>(&h);
#else
  return rn_pair16(v0, v1);
#endif
}

// pk layout (dwords): layer*32768 + kc*4096 + nt*256 + lane*4 + d; w_out at 5*32768.
// word d of lane(quad,n16) = M[kb][n] lo16 | M[kb+1][n] hi16, kb=kc*32+quad*8+2d, n=nt*16+n16.
#define NPROD 384

__global__ __launch_bounds__(256, 4) void mono_k(
    const float* __restrict__ x, unsigned* __restrict__ pk,
    unsigned* __restrict__ sem,
    const float* __restrict__ w_in, const float* __restrict__ w_out,
    const float* __restrict__ w1, const float* __restrict__ w2,
    const float* __restrict__ w3, const float* __restrict__ w4,
    const float* __restrict__ b_in,
    const float* __restrict__ b1, const float* __restrict__ b2,
    const float* __restrict__ b3, const float* __restrict__ b4,
    const float* __restrict__ b_out, float* __restrict__ out) {
  constexpr int MT = 4;
  constexpr int NR = MT * 16;
  __shared__ unsigned short zpl[NR * 256];  // 32 KB; phase-1 slab overlays the front
  const int t = threadIdx.x;
  const int bid = blockIdx.x;
  const int ln = t & 63;
  const int wv = t >> 6;
  const int quad = ln >> 4;
  const int n16 = ln & 15;
  const int grow0 = bid * NR;

  // ================= phase 1 (blocks 0..383) =================
  if (bid < NPROD) {
    if (bid >= 256) {
      // ---- pack w_in (32768 dwords) + w_out (2048 dwords at 5*32768) ----
      int idx = (bid - 256) * 256 + t;  // 0..32767
      {
        int kc = idx >> 12;
        int nt = (idx >> 8) & 15;
        int lane = (idx >> 2) & 63;
        int d = idx & 3;
        int n = nt * 16 + (lane & 15);
        int kb = kc * 32 + (lane >> 4) * 8 + d * 2;
        pk[idx] = rn_pair16(w_in[kb * 256 + n], w_in[(kb + 1) * 256 + n]);
      }
      int idx2 = idx + 32768;
      if (idx2 < 34816) {
        int r2 = idx2 - 32768;
        int kc = r2 >> 8;
        int lane = (r2 >> 2) & 63;
        int d = r2 & 3;
        int n = lane & 15;
        int kb = kc * 32 + (lane >> 4) * 8 + d * 2;
        float v0 = (n < 10) ? w_out[kb * 10 + n] : 0.0f;
        float v1 = (n < 10) ? w_out[(kb + 1) * 10 + n] : 0.0f;
        pk[5 * 32768 + r2] = rn_pair16(v0, v1);
      }
    } else {
      // ---- degree-5 polynomial inverse, 4-row slab ----
      const int m = bid >> 6;           // matrix 0..3
      const int r0 = (bid & 63) * 4;    // slab start row
      const float* __restrict__ W = (m == 0) ? w1 : (m == 1) ? w2 : (m == 2) ? w3 : w4;
      float* S = (float*)zpl;           // [4][256] overlay
#pragma unroll
      for (int i = 0; i < 4; ++i) {
        int e = i * 256 + t;
        int r = e >> 8, c = e & 255;
        S[r * 256 + c] = (((r0 + r) == c) ? 6.0f : 0.0f) - W[(r0 + r) * 256 + c];
      }
      __syncthreads();
      const float coef[4] = {-15.0f, 20.0f, -15.0f, 6.0f};
#pragma unroll
      for (int step = 0; step < 4; ++step) {
        float acc[4];
#pragma unroll
        for (int r = 0; r < 4; ++r) acc[r] = 0.0f;
        for (int k = 0; k < 256; k += 4) {
          float4 sv[4];
#pragma unroll
          for (int r = 0; r < 4; ++r) sv[r] = *(const float4*)&S[r * 256 + k];
          float wv0 = W[(k + 0) * 256 + t];
          float wv1 = W[(k + 1) * 256 + t];
          float wv2 = W[(k + 2) * 256 + t];
          float wv3 = W[(k + 3) * 256 + t];
#pragma unroll
          for (int r = 0; r < 4; ++r) {
            acc[r] = fmaf(sv[r].x, wv0, acc[r]);
            acc[r] = fmaf(sv[r].y, wv1, acc[r]);
            acc[r] = fmaf(sv[r].z, wv2, acc[r]);
            acc[r] = fmaf(sv[r].w, wv3, acc[r]);
          }
        }
        __syncthreads();
        float cdiag = coef[step];
#pragma unroll
        for (int r = 0; r < 4; ++r)
          S[r * 256 + t] = acc[r] + (((r0 + r) == t) ? cdiag : 0.0f);
        __syncthreads();
      }
      // pack slab: kc=r0>>5, quad=(r0>>3)&3, d in {d0,d0+1}, d0=(r0&7)>>1
      const int kc = r0 >> 5;
      const int q4 = (r0 >> 3) & 3;
      const int d0 = (r0 & 7) >> 1;
#pragma unroll
      for (int i = 0; i < 2; ++i) {
        int q = i * 256 + t;        // nt*32 + nn*2 + dd
        int nt = q >> 5;
        int nn = (q >> 1) & 15;
        int dd = q & 1;
        unsigned word = rn_pair16(S[(2 * dd) * 256 + nt * 16 + nn],
                                  S[(2 * dd + 1) * 256 + nt * 16 + nn]);
        pk[(m + 1) * 32768 + kc * 4096 + nt * 256 + (q4 * 16 + nn) * 4 + (d0 + dd)] = word;
      }
    }
    // release: all pk writes of this block device-visible, then bump semaphore
    __syncthreads();
    if (t == 0) {
      __threadfence();                 // agent-scope release (L2 writeback)
      atomicAdd(sem, 1u);              // device-scope by default
    }
    __syncthreads();                   // S-overlay reads done before x staging
  }

  // ================= stage x (all blocks; overlaps phase 1) =================
#pragma unroll
  for (int i = 0; i < MT * 4; ++i) {
    int e = i * 1024 + t * 4;
    int r = e >> 8, c = e & 255;
    float4 v = *(const float4*)(x + (grow0 + r) * 256 + c);
    int idx = r * 256 + (((c >> 3) ^ (r & 31)) * 8) + (c & 7);
    uint2 zp;
    zp.x = rtz_pair16(v.x, v.y);
    zp.y = rtz_pair16(v.z, v.w);
    *(uint2*)&zpl[idx] = zp;
  }

  // ================= acquire: wait for all producers =================
  if (t == 0) {
    while (__hip_atomic_load(sem, __ATOMIC_RELAXED, __HIP_MEMORY_SCOPE_AGENT) < NPROD)
      __builtin_amdgcn_s_sleep(2);
    __threadfence();                   // agent-scope acquire (invalidate L1/L2)
  }
  __syncthreads();                     // also orders x-staging before K-loop

  // ================= fused pipeline (round-14, proven) =================
  const float* bnv[4] = {b1, b2, b3, b4};
  f32x4 acc[MT][4];

  for (int layer = 0; layer < 5; ++layer) {
    const unsigned* pkl = pk + layer * 32768 + wv * 1024 + ln * 4;
#pragma unroll
    for (int mt = 0; mt < MT; ++mt)
#pragma unroll
      for (int nt = 0; nt < 4; ++nt) acc[mt][nt] = (f32x4){0.f, 0.f, 0.f, 0.f};

#pragma unroll 2
    for (int kc = 0; kc < 8; ++kc) {
      short8 wh[4], zf[MT];
      const unsigned* pb = pkl + kc * 4096;
#pragma unroll
      for (int nt = 0; nt < 4; ++nt) wh[nt] = *(const short8*)(pb + nt * 256);
#pragma unroll
      for (int mt = 0; mt < MT; ++mt) {
        int mm = mt * 16 + n16;
        int idx = mm * 256 + (((kc * 4 + quad) ^ (mm & 31)) * 8);
        zf[mt] = *(const short8*)&zpl[idx];
      }
#pragma unroll
      for (int mt = 0; mt < MT; ++mt)
#pragma unroll
        for (int nt = 0; nt < 4; ++nt)
          acc[mt][nt] = __builtin_amdgcn_mfma_f32_16x16x32_f16(wh[nt], zf[mt], acc[mt][nt], 0, 0, 0);
    }
    __syncthreads();  // all z reads of this layer done

#pragma unroll
    for (int nt = 0; nt < 4; ++nt) {
      int colb = wv * 64 + nt * 16 + quad * 4;
      float4 bi = make_float4(0.f, 0.f, 0.f, 0.f);
      float4 bn4 = bi;
      if (layer == 0) bi = *(const float4*)(b_in + colb);
      if (layer < 4) bn4 = *(const float4*)(bnv[layer] + colb);
#pragma unroll
      for (int mt = 0; mt < MT; ++mt) {
        int row = mt * 16 + n16;
        float v0 = acc[mt][nt][0] + bi.x;
        float v1 = acc[mt][nt][1] + bi.y;
        float v2 = acc[mt][nt][2] + bi.z;
        float v3 = acc[mt][nt][3] + bi.w;
        if (layer < 4) {
          v0 = v0 + tanh_fast(v0) + bn4.x;
          v1 = v1 + tanh_fast(v1) + bn4.y;
          v2 = v2 + tanh_fast(v2) + bn4.z;
          v3 = v3 + tanh_fast(v3) + bn4.w;
        }
        int idx = row * 256 + (((colb >> 3) ^ (row & 31)) * 8) + (colb & 7);
        uint2 zp;
        zp.x = rtz_pair16(v0, v1);
        zp.y = rtz_pair16(v2, v3);
        *(uint2*)&zpl[idx] = zp;
      }
    }
    __syncthreads();
  }

  // ---- logits: wave w reduces k-slice [w*64, w*64+64) ----
  f32x4 lacc[MT];
#pragma unroll
  for (int mt = 0; mt < MT; ++mt) lacc[mt] = (f32x4){0.f, 0.f, 0.f, 0.f};
  const unsigned* pw = pk + 5 * 32768 + ln * 4;
#pragma unroll
  for (int kk = 0; kk < 2; ++kk) {
    int kc = wv * 2 + kk;
    short8 wh = *(const short8*)(pw + kc * 256);
#pragma unroll
    for (int mt = 0; mt < MT; ++mt) {
      int mm = mt * 16 + n16;
      int idx = mm * 256 + (((kc * 4 + quad) ^ (mm & 31)) * 8);
      short8 zf = *(const short8*)&zpl[idx];
      lacc[mt] = __builtin_amdgcn_mfma_f32_16x16x32_f16(wh, zf, lacc[mt], 0, 0, 0);
    }
  }
  __syncthreads();
  float* pbuf = (float*)zpl;  // [wave][NR][16] floats
#pragma unroll
  for (int mt = 0; mt < MT; ++mt) {
    int addr = wv * (NR * 16) + (mt * 16 + n16) * 16 + quad * 4;
    *(f32x4*)&pbuf[addr] = lacc[mt];
  }
  __syncthreads();
  if (t < NR) {
    int r = t;
    float lg[10];
    float mx = -1e30f;
#pragma unroll
    for (int j = 0; j < 10; ++j) {
      float s = b_out[j];
#pragma unroll
      for (int w2 = 0; w2 < 4; ++w2) s += pbuf[w2 * (NR * 16) + r * 16 + j];
      lg[j] = s;
      mx = fmaxf(mx, s);
    }
    float sum = 0.f;
#pragma unroll
    for (int j = 0; j < 10; ++j) {
      lg[j] = __expf(lg[j] - mx);
      sum += lg[j];
    }
    float inv = 1.0f / sum;
    float* op = out + (grow0 + r) * 10;
#pragma unroll
    for (int j = 0; j < 10; ++j) op[j] = lg[j] * inv;
  }
}

extern "C" void kernel_launch(void* const* d_in, const int* in_sizes, int n_in,
                              void* d_out, int out_size, void* d_ws, size_t ws_size,
                              hipStream_t stream) {
  const float* x     = (const float*)d_in[0];
  const float* w_in  = (const float*)d_in[1];
  const float* b_in  = (const float*)d_in[2];
  const float* w_out = (const float*)d_in[3];
  const float* b_out = (const float*)d_in[4];
  const float* w1 = (const float*)d_in[5];
  const float* b1 = (const float*)d_in[6];
  const float* w2 = (const float*)d_in[7];
  const float* b2 = (const float*)d_in[8];
  const float* w3 = (const float*)d_in[9];
  const float* b3 = (const float*)d_in[10];
  const float* w4 = (const float*)d_in[11];
  const float* b4 = (const float*)d_in[12];
  float* out = (float*)d_out;

  unsigned* pk = (unsigned*)d_ws;          // 165888 dwords
  unsigned* sem = pk + 165888;             // 1 dword semaphore

  hipMemsetAsync(sem, 0, 4, stream);       // graph-capturable async memset
  mono_k<<<1024, 256, 0, stream>>>(x, pk, sem, w_in, w_out,
                                   w1, w2, w3, w4,
                                   b_in, b1, b2, b3, b4, b_out, out);
}